// Round 2
// baseline (1477.332 us; speedup 1.0000x reference)
//
#include <hip/hip_runtime.h>
#include <hip/hip_bf16.h>

#define NN 100000
#define NE 800000
#define FIN 16
#define H 64
#define NL 4
#define CDIM 8

__device__ __forceinline__ float elu(float x) { return x > 0.f ? x : expm1f(x); }

__global__ __launch_bounds__(256) void k_zero_cnt(int* cnt) {
    int i = blockIdx.x * 256 + threadIdx.x;
    if (i < NN) cnt[i] = 0;
}

__global__ __launch_bounds__(256) void k_count(const int* __restrict__ row, int* cnt) {
    int e = blockIdx.x * 256 + threadIdx.x;
    if (e < NE) atomicAdd(&cnt[row[e]], 1);
}

__global__ __launch_bounds__(256) void k_invcnt(const int* __restrict__ cnt, float* inv) {
    int i = blockIdx.x * 256 + threadIdx.x;
    if (i < NN) inv[i] = 1.f / fmaxf((float)cnt[i], 1.f);
}

// h = ELU(x @ w1 + b1)   x:(N,16) fp32, w1:(16,64)
__global__ __launch_bounds__(256) void k_enc1(const float* __restrict__ x,
                                              const float* __restrict__ w1,
                                              const float* __restrict__ b1,
                                              float* __restrict__ h) {
    __shared__ float w1s[FIN * H];
    int tid = threadIdx.x;
    int q = tid >> 6, j = tid & 63;
    int n = blockIdx.x * 4 + q;
    for (int t = tid; t < FIN * H; t += 256) w1s[t] = w1[t];
    __syncthreads();
    float acc = b1[j];
#pragma unroll
    for (int k = 0; k < FIN; k++) acc += x[n * FIN + k] * w1s[k * H + j];
    h[n * H + j] = elu(acc);
}

// feats = ELU(h @ w2 + b2)   w2:(64,64)
__global__ __launch_bounds__(256) void k_enc2(const float* __restrict__ h,
                                              const float* __restrict__ w2,
                                              const float* __restrict__ b2,
                                              float* __restrict__ feats) {
    __shared__ float w2s[H * H];
    __shared__ float hs[4][H];
    int tid = threadIdx.x;
    int q = tid >> 6, j = tid & 63;
    int n = blockIdx.x * 4 + q;
    for (int t = tid; t < H * H; t += 256) w2s[t] = w2[t];
    hs[q][j] = h[n * H + j];
    __syncthreads();
    float acc = b2[j];
    const float* hr = hs[q];
#pragma unroll
    for (int k = 0; k < H; k++) acc += hr[k] * w2s[k * H + j];
    feats[n * H + j] = elu(acc);
}

// A = feats @ (Wtop - Wbot) + conv_b ;  B = feats @ Wbot
__global__ __launch_bounds__(256) void k_ab(const float* __restrict__ feats,
                                            const float* __restrict__ convw,
                                            const float* __restrict__ convb,
                                            float* __restrict__ A, float* __restrict__ Bm) {
    __shared__ float ws[2 * H * H];  // 128x64 fp32 = 32 KB
    __shared__ float fs[4][H];
    int tid = threadIdx.x;
    int q = tid >> 6, j = tid & 63;
    int n = blockIdx.x * 4 + q;
    for (int t = tid; t < 2 * H * H; t += 256) ws[t] = convw[t];
    fs[q][j] = feats[n * H + j];
    __syncthreads();
    float a = convb[j];
    float b = 0.f;
    const float* fr = fs[q];
#pragma unroll
    for (int k = 0; k < H; k++) {
        float f = fr[k];
        float wt = ws[k * H + j];
        float wb = ws[(H + k) * H + j];
        a += f * (wt - wb);
        b += f * wb;
    }
    A[n * H + j] = a;
    Bm[n * H + j] = b;
}

// per edge: val = (ELU(A[row]+B[col]) * bn_scale*gamma + beta) * inv_cnt[row];
// feats[row] += val   (in-place residual: k_edge never reads feats)
__global__ __launch_bounds__(256) void k_edge(const float* __restrict__ A,
                                              const float* __restrict__ Bm,
                                              const int* __restrict__ row,
                                              const int* __restrict__ col,
                                              const float* __restrict__ inv_cnt,
                                              const float* __restrict__ gamma,
                                              const float* __restrict__ beta,
                                              float* feats) {
    int tid = threadIdx.x;
    int e = blockIdx.x * 4 + (tid >> 6);
    int j = tid & 63;
    int r = row[e], c = col[e];
    float v = A[r * H + j] + Bm[c * H + j];
    v = elu(v);
    const float bn_scale = 0.99999500003749968750f;  // 1/sqrt(1+1e-5)
    v = v * (bn_scale * gamma[j]) + beta[j];
    v *= inv_cnt[r];
    atomicAdd(&feats[r * H + j], v);
}

// 3-layer MLP head, fused; writes fp32 out (N, 8)
__global__ __launch_bounds__(256) void k_head(const float* __restrict__ feats,
                                              const float* __restrict__ w1,
                                              const float* __restrict__ b1,
                                              const float* __restrict__ w2,
                                              const float* __restrict__ b2,
                                              const float* __restrict__ w3,
                                              const float* __restrict__ b3,
                                              float* __restrict__ out) {
    __shared__ float w1s[64 * 64];
    __shared__ float w2s[64 * 32];
    __shared__ float w3s[32 * 8];
    __shared__ float b1s[64], b2s[32], b3s[8];
    __shared__ float fs[4][64], o1[4][64], o2[4][32];
    int tid = threadIdx.x;
    int q = tid >> 6, j = tid & 63;
    int n = blockIdx.x * 4 + q;
    for (int t = tid; t < 4096; t += 256) w1s[t] = w1[t];
    for (int t = tid; t < 2048; t += 256) w2s[t] = w2[t];
    if (tid < 256) w3s[tid] = w3[tid];
    if (tid < 64) b1s[tid] = b1[tid];
    if (tid < 32) b2s[tid] = b2[tid];
    if (tid < 8) b3s[tid] = b3[tid];
    fs[q][j] = feats[n * 64 + j];
    __syncthreads();
    float acc = b1s[j];
#pragma unroll
    for (int k = 0; k < 64; k++) acc += fs[q][k] * w1s[k * 64 + j];
    o1[q][j] = elu(acc);
    __syncthreads();
    if (j < 32) {
        float a2 = b2s[j];
#pragma unroll
        for (int k = 0; k < 64; k++) a2 += o1[q][k] * w2s[k * 32 + j];
        o2[q][j] = elu(a2);
    }
    __syncthreads();
    if (j < 8) {
        float a3 = b3s[j];
#pragma unroll
        for (int k = 0; k < 32; k++) a3 += o2[q][k] * w3s[k * 8 + j];
        out[n * 8 + j] = a3;
    }
}

__global__ __launch_bounds__(256) void k_batch(const int* __restrict__ batch,
                                               float* __restrict__ out) {
    int i = blockIdx.x * 256 + threadIdx.x;
    if (i < NN) out[i] = (float)batch[i];
}

extern "C" void kernel_launch(void* const* d_in, const int* in_sizes, int n_in,
                              void* d_out, int out_size, void* d_ws, size_t ws_size,
                              hipStream_t stream) {
    const float* x = (const float*)d_in[0];
    const int* edge_index = (const int*)d_in[1];
    const int* batch = (const int*)d_in[2];
    const float* enc_w1 = (const float*)d_in[3];
    const float* enc_b1 = (const float*)d_in[4];
    const float* enc_w2 = (const float*)d_in[5];
    const float* enc_b2 = (const float*)d_in[6];
    const float* conv_w = (const float*)d_in[7];
    const float* conv_b = (const float*)d_in[8];
    const float* bn_gamma = (const float*)d_in[9];
    const float* bn_beta = (const float*)d_in[10];
    const float* out_w1 = (const float*)d_in[11];
    const float* out_b1 = (const float*)d_in[12];
    const float* out_w2 = (const float*)d_in[13];
    const float* out_b2 = (const float*)d_in[14];
    const float* out_w3 = (const float*)d_in[15];
    const float* out_b3 = (const float*)d_in[16];

    const int* row = edge_index;
    const int* col = edge_index + NE;

    float* feats = (float*)d_ws;                    // N*H fp32
    float* Abuf = feats + (size_t)NN * H;           // N*H fp32
    float* Bbuf = Abuf + (size_t)NN * H;            // N*H fp32
    int* cnt = (int*)(Bbuf + (size_t)NN * H);       // N int
    float* inv = (float*)(cnt + NN);                // N fp32
    float* h = Abuf;  // encoder hidden reuses A

    float* out = (float*)d_out;

    k_zero_cnt<<<(NN + 255) / 256, 256, 0, stream>>>(cnt);
    k_count<<<(NE + 255) / 256, 256, 0, stream>>>(row, cnt);
    k_invcnt<<<(NN + 255) / 256, 256, 0, stream>>>(cnt, inv);

    k_enc1<<<NN / 4, 256, 0, stream>>>(x, enc_w1, enc_b1, h);
    k_enc2<<<NN / 4, 256, 0, stream>>>(h, enc_w2, enc_b2, feats);

    for (int i = 0; i < NL; i++) {
        k_ab<<<NN / 4, 256, 0, stream>>>(feats, conv_w + (size_t)i * 2 * H * H,
                                         conv_b + (size_t)i * H, Abuf, Bbuf);
        k_edge<<<NE / 4, 256, 0, stream>>>(Abuf, Bbuf, row, col, inv,
                                           bn_gamma + (size_t)i * H,
                                           bn_beta + (size_t)i * H, feats);
    }

    k_head<<<NN / 4, 256, 0, stream>>>(feats, out_w1, out_b1, out_w2, out_b2,
                                       out_w3, out_b3, out);
    k_batch<<<(NN + 255) / 256, 256, 0, stream>>>(batch, out + (size_t)NN * CDIM);
}

// Round 3
// 1297.394 us; speedup vs baseline: 1.1387x; 1.1387x over previous
//
#include <hip/hip_runtime.h>

#define NN 100000
#define NE 800000
#define FIN 16
#define H 64
#define NL 4
#define CDIM 8
#define SCAN_BLOCKS ((NN + 255) / 256)  // 391

__device__ __forceinline__ float elu(float x) { return x > 0.f ? x : expm1f(x); }

__global__ __launch_bounds__(256) void k_zero_cnt(int* cnt) {
    int i = blockIdx.x * 256 + threadIdx.x;
    if (i < NN) cnt[i] = 0;
}

__global__ __launch_bounds__(256) void k_count(const int* __restrict__ row, int* cnt) {
    int e = blockIdx.x * 256 + threadIdx.x;
    if (e < NE) atomicAdd(&cnt[row[e]], 1);
}

// block-level exclusive scan (256/block); row_ptr gets local exclusive prefix
__global__ __launch_bounds__(256) void k_scan1(const int* __restrict__ cnt,
                                               int* __restrict__ row_ptr,
                                               int* __restrict__ bsum) {
    __shared__ int s[256];
    int t = threadIdx.x, i = blockIdx.x * 256 + t;
    int v = (i < NN) ? cnt[i] : 0;
    s[t] = v;
    __syncthreads();
    for (int off = 1; off < 256; off <<= 1) {
        int x = (t >= off) ? s[t - off] : 0;
        __syncthreads();
        s[t] += x;
        __syncthreads();
    }
    if (i < NN) row_ptr[i] = s[t] - v;  // exclusive
    if (t == 255) bsum[blockIdx.x] = s[255];
}

// scan the 391 block sums (single block, 512 threads)
__global__ __launch_bounds__(512) void k_scan2(const int* __restrict__ bsum,
                                               int* __restrict__ bbase) {
    __shared__ int s[512];
    int t = threadIdx.x;
    int v = (t < SCAN_BLOCKS) ? bsum[t] : 0;
    s[t] = v;
    __syncthreads();
    for (int off = 1; off < 512; off <<= 1) {
        int x = (t >= off) ? s[t - off] : 0;
        __syncthreads();
        s[t] += x;
        __syncthreads();
    }
    if (t < SCAN_BLOCKS) bbase[t] = s[t] - v;  // exclusive
}

__global__ __launch_bounds__(256) void k_scan3(int* __restrict__ row_ptr,
                                               const int* __restrict__ bbase,
                                               int* __restrict__ woff) {
    int t = threadIdx.x, i = blockIdx.x * 256 + t;
    if (i < NN) {
        int v = row_ptr[i] + bbase[blockIdx.x];
        row_ptr[i] = v;
        woff[i] = v;
    }
    if (i == 0) row_ptr[NN] = NE;
}

__global__ __launch_bounds__(256) void k_scatter(const int* __restrict__ row,
                                                 const int* __restrict__ col,
                                                 int* woff, int* __restrict__ cols) {
    int e = blockIdx.x * 256 + threadIdx.x;
    if (e < NE) {
        int r = row[e];
        int p = atomicAdd(&woff[r], 1);
        cols[p] = col[e];
    }
}

// h = ELU(x @ w1 + b1)   x:(N,16)
__global__ __launch_bounds__(256) void k_enc1(const float* __restrict__ x,
                                              const float* __restrict__ w1,
                                              const float* __restrict__ b1,
                                              float* __restrict__ h) {
    __shared__ float w1s[FIN * H];
    int tid = threadIdx.x;
    int q = tid >> 6, j = tid & 63;
    for (int t = tid; t < FIN * H; t += 256) w1s[t] = w1[t];
    __syncthreads();
    float bb = b1[j];
    int base = blockIdx.x * 32;
    for (int i = 0; i < 8; i++) {
        int n = base + i * 4 + q;
        float acc = bb;
#pragma unroll
        for (int k = 0; k < FIN; k++) acc += x[n * FIN + k] * w1s[k * H + j];
        h[n * H + j] = elu(acc);
    }
}

// feats = ELU(h @ w2 + b2), 32 nodes/block, shfl row-broadcast
__global__ __launch_bounds__(256) void k_enc2(const float* __restrict__ h,
                                              const float* __restrict__ w2,
                                              const float* __restrict__ b2,
                                              float* __restrict__ feats) {
    __shared__ float ws[H * H];
    int tid = threadIdx.x;
    int q = tid >> 6, j = tid & 63;
    for (int t = tid; t < H * H; t += 256) ws[t] = w2[t];
    __syncthreads();
    float bb = b2[j];
    int base = blockIdx.x * 32;
    for (int i = 0; i < 8; i++) {
        int n = base + i * 4 + q;
        float f = h[n * H + j];
        float acc = bb;
#pragma unroll
        for (int k = 0; k < H; k++) acc += __shfl(f, k) * ws[k * H + j];
        feats[n * H + j] = elu(acc);
    }
}

// A = feats @ (Wt - Wb) + conv_b ;  B = feats @ Wb ;  32 nodes/block
__global__ __launch_bounds__(256) void k_ab(const float* __restrict__ feats,
                                            const float* __restrict__ convw,
                                            const float* __restrict__ convb,
                                            float* __restrict__ A, float* __restrict__ Bm) {
    __shared__ float ws[2 * H * H];  // 32 KB
    int tid = threadIdx.x;
    int q = tid >> 6, j = tid & 63;
    for (int t = tid; t < 2 * H * H; t += 256) ws[t] = convw[t];
    __syncthreads();
    for (int t = tid; t < H * H; t += 256) ws[t] -= ws[H * H + t];  // top := Wt - Wb
    __syncthreads();
    float cb = convb[j];
    int base = blockIdx.x * 32;
    for (int i = 0; i < 8; i++) {
        int n = base + i * 4 + q;
        float f = feats[n * H + j];
        float a = cb, b = 0.f;
#pragma unroll
        for (int k = 0; k < H; k++) {
            float fk = __shfl(f, k);
            a += fk * ws[k * H + j];
            b += fk * ws[H * H + k * H + j];
        }
        A[n * H + j] = a;
        Bm[n * H + j] = b;
    }
}

// CSR gather: one wave per node, lane = feature column. No atomics.
__global__ __launch_bounds__(256) void k_gather(const float* __restrict__ A,
                                                const float* __restrict__ Bm,
                                                const int* __restrict__ row_ptr,
                                                const int* __restrict__ cols,
                                                const float* __restrict__ gamma,
                                                const float* __restrict__ beta,
                                                float* __restrict__ feats) {
    int tid = threadIdx.x;
    int q = tid >> 6, j = tid & 63;
    int n = blockIdx.x * 4 + q;
    int s = row_ptr[n], e = row_ptr[n + 1];
    float a = A[n * H + j];
    float acc = 0.f;
    for (int p = s; p < e; p++) {
        int c = cols[p];
        acc += elu(a + Bm[c * H + j]);
    }
    int cn = e - s;
    const float bs = 0.99999500003749968750f;  // 1/sqrt(1+1e-5)
    float add = (cn > 0) ? acc * (bs * gamma[j]) / (float)cn + beta[j] : 0.f;
    feats[n * H + j] += add;
}

// 3-layer head, 32 nodes/block, pure shfl (no inner barriers)
__global__ __launch_bounds__(256) void k_head(const float* __restrict__ feats,
                                              const float* __restrict__ w1,
                                              const float* __restrict__ b1,
                                              const float* __restrict__ w2,
                                              const float* __restrict__ b2,
                                              const float* __restrict__ w3,
                                              const float* __restrict__ b3,
                                              float* __restrict__ out) {
    __shared__ float w1s[64 * 64];
    __shared__ float w2s[64 * 32];
    __shared__ float w3s[32 * 8];
    __shared__ float b1s[64], b2s[32], b3s[8];
    int tid = threadIdx.x;
    int q = tid >> 6, j = tid & 63;
    for (int t = tid; t < 4096; t += 256) w1s[t] = w1[t];
    for (int t = tid; t < 2048; t += 256) w2s[t] = w2[t];
    if (tid < 256) w3s[tid] = w3[tid];
    if (tid < 64) b1s[tid] = b1[tid];
    if (tid < 32) b2s[tid] = b2[tid];
    if (tid < 8) b3s[tid] = b3[tid];
    __syncthreads();
    int base = blockIdx.x * 32;
    for (int i = 0; i < 8; i++) {
        int n = base + i * 4 + q;
        float f = feats[n * 64 + j];
        float acc = b1s[j];
#pragma unroll
        for (int k = 0; k < 64; k++) acc += __shfl(f, k) * w1s[k * 64 + j];
        float o1 = elu(acc);
        int j2 = j & 31;
        float a2 = b2s[j2];
#pragma unroll
        for (int k = 0; k < 64; k++) a2 += __shfl(o1, k) * w2s[k * 32 + j2];
        float o2 = elu(a2);  // lanes 32..63 duplicate lanes 0..31
        int j3 = j & 7;
        float a3 = b3s[j3];
#pragma unroll
        for (int k = 0; k < 32; k++) a3 += __shfl(o2, k) * w3s[k * 8 + j3];
        if (j < 8) out[n * 8 + j] = a3;
    }
}

__global__ __launch_bounds__(256) void k_batch(const int* __restrict__ batch,
                                               float* __restrict__ out) {
    int i = blockIdx.x * 256 + threadIdx.x;
    if (i < NN) out[i] = (float)batch[i];
}

extern "C" void kernel_launch(void* const* d_in, const int* in_sizes, int n_in,
                              void* d_out, int out_size, void* d_ws, size_t ws_size,
                              hipStream_t stream) {
    const float* x = (const float*)d_in[0];
    const int* edge_index = (const int*)d_in[1];
    const int* batch = (const int*)d_in[2];
    const float* enc_w1 = (const float*)d_in[3];
    const float* enc_b1 = (const float*)d_in[4];
    const float* enc_w2 = (const float*)d_in[5];
    const float* enc_b2 = (const float*)d_in[6];
    const float* conv_w = (const float*)d_in[7];
    const float* conv_b = (const float*)d_in[8];
    const float* bn_gamma = (const float*)d_in[9];
    const float* bn_beta = (const float*)d_in[10];
    const float* out_w1 = (const float*)d_in[11];
    const float* out_b1 = (const float*)d_in[12];
    const float* out_w2 = (const float*)d_in[13];
    const float* out_b2 = (const float*)d_in[14];
    const float* out_w3 = (const float*)d_in[15];
    const float* out_b3 = (const float*)d_in[16];

    const int* row = edge_index;
    const int* col = edge_index + NE;

    float* feats = (float*)d_ws;               // N*H
    float* Abuf = feats + (size_t)NN * H;      // N*H
    float* Bbuf = Abuf + (size_t)NN * H;       // N*H
    int* cnt = (int*)(Bbuf + (size_t)NN * H);  // N
    int* row_ptr = cnt + NN;                   // N+1
    int* woff = row_ptr + NN + 1;              // N
    int* cols = woff + NN;                     // E
    int* bsum = cols + NE;                     // 512
    int* bbase = bsum + 512;                   // 512
    float* h = Abuf;                           // encoder hidden reuses A

    float* out = (float*)d_out;

    // CSR build
    k_zero_cnt<<<(NN + 255) / 256, 256, 0, stream>>>(cnt);
    k_count<<<(NE + 255) / 256, 256, 0, stream>>>(row, cnt);
    k_scan1<<<SCAN_BLOCKS, 256, 0, stream>>>(cnt, row_ptr, bsum);
    k_scan2<<<1, 512, 0, stream>>>(bsum, bbase);
    k_scan3<<<SCAN_BLOCKS, 256, 0, stream>>>(row_ptr, bbase, woff);
    k_scatter<<<(NE + 255) / 256, 256, 0, stream>>>(row, col, woff, cols);

    // encoder
    k_enc1<<<NN / 32, 256, 0, stream>>>(x, enc_w1, enc_b1, h);
    k_enc2<<<NN / 32, 256, 0, stream>>>(h, enc_w2, enc_b2, feats);

    // conv layers (in-place residual accumulate into feats)
    for (int i = 0; i < NL; i++) {
        k_ab<<<NN / 32, 256, 0, stream>>>(feats, conv_w + (size_t)i * 2 * H * H,
                                          conv_b + (size_t)i * H, Abuf, Bbuf);
        k_gather<<<NN / 4, 256, 0, stream>>>(Abuf, Bbuf, row_ptr, cols,
                                             bn_gamma + (size_t)i * H,
                                             bn_beta + (size_t)i * H, feats);
    }

    k_head<<<NN / 32, 256, 0, stream>>>(feats, out_w1, out_b1, out_w2, out_b2,
                                        out_w3, out_b3, out);
    k_batch<<<(NN + 255) / 256, 256, 0, stream>>>(batch, out + (size_t)NN * CDIM);
}